// Round 1
// baseline (1146.277 us; speedup 1.0000x reference)
//
#include <hip/hip_runtime.h>
#include <stdint.h>

typedef __attribute__((ext_vector_type(4))) float f32x4;
typedef __attribute__((ext_vector_type(8))) short s16x8;
typedef __attribute__((ext_vector_type(4))) short s16x4;
typedef __bf16 bf16x8 __attribute__((ext_vector_type(8)));

#define N_NODES 1000000
#define MEM_DIM 128
#define MSG_DIM 256
#define N_UP    200000
#define NG      384   /* 3*MEM_DIM */

__device__ __forceinline__ short f2bf(float f) {
  uint32_t u = __builtin_bit_cast(uint32_t, f);
  u += 0x7FFFu + ((u >> 16) & 1u);   // round-to-nearest-even
  return (short)(u >> 16);
}
__device__ __forceinline__ float bf2f(short s) {
  uint32_t u = ((uint32_t)(uint16_t)s) << 16;
  return __builtin_bit_cast(float, u);
}

__device__ __forceinline__ f32x4 mfma16(s16x8 a, s16x8 b, f32x4 c) {
  return __builtin_amdgcn_mfma_f32_16x16x32_bf16(
      __builtin_bit_cast(bf16x8, a), __builtin_bit_cast(bf16x8, b), c, 0, 0, 0);
}

// ---------------- prep: weights fp32 -> bf16 in ws ----------------
__global__ void prep_weights(const float* __restrict__ W_ih,
                             const float* __restrict__ W_hh,
                             short* __restrict__ wbf) {
  int i = blockIdx.x * 256 + threadIdx.x;
  const int n_ih = NG * MSG_DIM;                 // 98304
  const int n_hh = NG * MEM_DIM;                 // 49152
  if (i < n_ih)            wbf[i] = f2bf(W_ih[i]);
  else if (i < n_ih + n_hh) wbf[i] = f2bf(W_hh[i - n_ih]);
}

// ---------------- bulk copy memory + last_update -> out ----------------
__global__ void copy_base(const float* __restrict__ mem,
                          const float* __restrict__ lu,
                          float* __restrict__ out) {
  const size_t MEMV = (size_t)N_NODES * MEM_DIM / 4;   // 32,000,000 float4
  const size_t LUV  = (size_t)N_NODES / 4;             // 250,000 float4
  size_t i = (size_t)blockIdx.x * 256 + threadIdx.x;
  if (i < MEMV) {
    ((f32x4*)out)[i] = ((const f32x4*)mem)[i];
  } else if (i < MEMV + LUV) {
    size_t j = i - MEMV;
    f32x4* outlu = (f32x4*)(out + (size_t)N_NODES * MEM_DIM);
    outlu[j] = ((const f32x4*)lu)[j];
  }
}

// ---------------- fused GRU + scatter ----------------
// block: 64 rows x 128 out-cols; 8 waves = 2(M) x 4(N); wave: 32x32 out tile
__launch_bounds__(512)
__global__ void gru_scatter(const float* __restrict__ mem,
                            const int*   __restrict__ ids,
                            const float* __restrict__ msgs,
                            const float* __restrict__ ts,
                            const short* __restrict__ wbf,   // [384][256] bf16 then [384][128] bf16
                            const float* __restrict__ b_ih,
                            const float* __restrict__ b_hh,
                            float* __restrict__ out_mem,
                            float* __restrict__ out_lu) {
  // padded +8 shorts per row: row strides 132/68 dwords -> 2-way bank alias (free)
  __shared__ short sMsg[64][MSG_DIM + 8];
  __shared__ short sH[64][MEM_DIM + 8];
  __shared__ int   sIds[64];

  const int tid = threadIdx.x;
  const int r0  = blockIdx.x * 64;

  if (tid < 64) sIds[tid] = ids[r0 + tid];

  // stage message tile: 64 x 256 fp32 -> bf16 (4096 float4 chunks)
  #pragma unroll
  for (int p = 0; p < 8; ++p) {
    int c = tid + p * 512;
    int row = c >> 6;
    int col = (c & 63) << 2;
    f32x4 v = *(const f32x4*)(msgs + (size_t)(r0 + row) * MSG_DIM + col);
    s16x4 o; o[0]=f2bf(v[0]); o[1]=f2bf(v[1]); o[2]=f2bf(v[2]); o[3]=f2bf(v[3]);
    *(s16x4*)&sMsg[row][col] = o;
  }
  // gather + stage h tile: 64 x 128 fp32 -> bf16 (2048 float4 chunks)
  #pragma unroll
  for (int p = 0; p < 4; ++p) {
    int c = tid + p * 512;
    int row = c >> 5;
    int col = (c & 31) << 2;
    int id  = ids[r0 + row];                      // L1-broadcast
    f32x4 v = *(const f32x4*)(mem + (size_t)id * MEM_DIM + col);
    s16x4 o; o[0]=f2bf(v[0]); o[1]=f2bf(v[1]); o[2]=f2bf(v[2]); o[3]=f2bf(v[3]);
    *(s16x4*)&sH[row][col] = o;
  }
  __syncthreads();

  const int lane = tid & 63;
  const int wave = tid >> 6;
  const int wm   = wave & 1;     // M half
  const int wn   = wave >> 1;    // N quarter (0..3)
  const int quad = lane >> 4;
  const int ln   = lane & 15;

  // acc[gate][mi][ni]: gates 0=r(combined) 1=z(combined) 2=i_n 3=h_n
  f32x4 acc[4][2][2] = {};

  const short* Wih = wbf;                         // [384][256]
  const short* Whh = wbf + NG * MSG_DIM;          // [384][128]

  // ---- message GEMM: K = 256 ----
  #pragma unroll
  for (int kc = 0; kc < 8; ++kc) {
    const int kk = kc * 32 + quad * 8;
    s16x8 a[2];
    #pragma unroll
    for (int mi = 0; mi < 2; ++mi)
      a[mi] = *(const s16x8*)&sMsg[wm * 32 + mi * 16 + ln][kk];
    #pragma unroll
    for (int g = 0; g < 3; ++g) {
      #pragma unroll
      for (int ni = 0; ni < 2; ++ni) {
        int nrow = g * 128 + wn * 32 + ni * 16 + ln;
        s16x8 b = *(const s16x8*)(Wih + (size_t)nrow * MSG_DIM + kk);
        #pragma unroll
        for (int mi = 0; mi < 2; ++mi)
          acc[g][mi][ni] = mfma16(a[mi], b, acc[g][mi][ni]);
      }
    }
  }
  // ---- hidden GEMM: K = 128; gates r,z combine; h_n separate (acc[3]) ----
  #pragma unroll
  for (int kc = 0; kc < 4; ++kc) {
    const int kk = kc * 32 + quad * 8;
    s16x8 a[2];
    #pragma unroll
    for (int mi = 0; mi < 2; ++mi)
      a[mi] = *(const s16x8*)&sH[wm * 32 + mi * 16 + ln][kk];
    #pragma unroll
    for (int g = 0; g < 3; ++g) {
      const int ag = (g == 2) ? 3 : g;
      #pragma unroll
      for (int ni = 0; ni < 2; ++ni) {
        int nrow = g * 128 + wn * 32 + ni * 16 + ln;
        s16x8 b = *(const s16x8*)(Whh + (size_t)nrow * MEM_DIM + kk);
        #pragma unroll
        for (int mi = 0; mi < 2; ++mi)
          acc[ag][mi][ni] = mfma16(a[mi], b, acc[ag][mi][ni]);
      }
    }
  }

  // ---- epilogue: gates + blend + scatter ----
  #pragma unroll
  for (int mi = 0; mi < 2; ++mi) {
    #pragma unroll
    for (int ni = 0; ni < 2; ++ni) {
      const int col = wn * 32 + ni * 16 + ln;
      const float br  = b_ih[col] + b_hh[col];
      const float bz  = b_ih[128 + col] + b_hh[128 + col];
      const float bin = b_ih[256 + col];
      const float bhn = b_hh[256 + col];
      #pragma unroll
      for (int rg = 0; rg < 4; ++rg) {
        const int rl = wm * 32 + mi * 16 + quad * 4 + rg;   // local row (C/D: row=quad*4+reg)
        float xr  = acc[0][mi][ni][rg] + br;
        float xz  = acc[1][mi][ni][rg] + bz;
        float xin = acc[2][mi][ni][rg] + bin;
        float xhn = acc[3][mi][ni][rg] + bhn;
        float r = 1.0f / (1.0f + __expf(-xr));
        float z = 1.0f / (1.0f + __expf(-xz));
        float e = __expf(2.0f * (xin + r * xhn));
        float n = 1.0f - 2.0f / (e + 1.0f);                 // tanh
        float h = bf2f(sH[rl][col]);
        out_mem[(size_t)sIds[rl] * MEM_DIM + col] = (1.0f - z) * n + z * h;
      }
    }
  }

  if (tid < 64) out_lu[sIds[tid]] = ts[r0 + tid];
}

extern "C" void kernel_launch(void* const* d_in, const int* in_sizes, int n_in,
                              void* d_out, int out_size, void* d_ws, size_t ws_size,
                              hipStream_t stream) {
  const float* mem  = (const float*)d_in[0];
  const float* lu   = (const float*)d_in[1];
  const int*   ids  = (const int*)  d_in[2];
  const float* msgs = (const float*)d_in[3];
  const float* ts   = (const float*)d_in[4];
  const float* W_ih = (const float*)d_in[5];
  const float* W_hh = (const float*)d_in[6];
  const float* b_ih = (const float*)d_in[7];
  const float* b_hh = (const float*)d_in[8];

  float* out_mem = (float*)d_out;
  float* out_lu  = out_mem + (size_t)N_NODES * MEM_DIM;
  short* wbf     = (short*)d_ws;   // 147456 bf16 = 294,912 B

  // weights -> bf16
  prep_weights<<<(NG * (MSG_DIM + MEM_DIM) + 255) / 256, 256, 0, stream>>>(W_ih, W_hh, wbf);

  // bulk copy: 32,250,000 float4
  {
    const size_t totv = (size_t)N_NODES * MEM_DIM / 4 + (size_t)N_NODES / 4;
    int grid = (int)((totv + 255) / 256);
    copy_base<<<grid, 256, 0, stream>>>(mem, lu, (float*)d_out);
  }

  // fused GRU + scatter (200000 / 64 = 3125 blocks)
  gru_scatter<<<N_UP / 64, 512, 0, stream>>>(mem, ids, msgs, ts, wbf,
                                             b_ih, b_hh, out_mem, out_lu);
}